// Round 1
// baseline (410.825 us; speedup 1.0000x reference)
//
#include <hip/hip_runtime.h>
#include <math.h>

// Problem constants (fixed by reference setup_inputs)
#define NN 8192
#define SS 32
#define DD 32
#define KK 1024
#define OUT_ELEMS ((size_t)NN * SS * DD)   // 8388608; loss scalar at out[OUT_ELEMS]

// loss = S * (1 + BETA) * sum_sq / (N*S*D)
#define LOSS_SCALE (32.0f * 1.001f / 8388608.0f)

typedef _Float16 half8 __attribute__((ext_vector_type(8)));
typedef float   floatx4 __attribute__((ext_vector_type(4)));

#define CH_TILES 8                    // k-tiles of 16 per chunk
#define CHUNK_K  (CH_TILES * 16)      // 128 codewords per chunk
#define NCHUNK   (KK / CHUNK_K)       // 8 chunks -> 8 barriers (was 16)
#define RG 4                          // 16-row groups per wave -> 64 rows/wave
#define NBLOCKS ((NN / 256) * SS)     // 1024 main blocks = 4 blocks/CU

// SESSION NOTE (R7): rocprof showed MfmaUtil 26% with MFMA work-floor ~26us of
// an 85us kernel -> latency-bound, not throughput-bound (VGPR was 44: zero ILP,
// per-tile ds_read->waitcnt->3-chained-MFMA->compare serial path). This version:
// RG=4 (4 independent acc chains, MFMAs grouped by hi/lo term), rolling register
// preload of next tile's B-fragments, CHUNK_K=128 (8 barriers), setprio around
// the MFMA cluster. Loss path (per-block partials + tiny reduce) unchanged.

__global__ __launch_bounds__(256, 4) void vq_fused(const float* __restrict__ z,
                                                   const float* __restrict__ W,
                                                   float* __restrict__ out,
                                                   float* __restrict__ part) {
    __shared__ _Float16 bufH[2][CH_TILES][64][8];   // 16 KB
    __shared__ _Float16 bufL[2][CH_TILES][64][8];   // 16 KB
    __shared__ float    w2b[2][CHUNK_K];            // 1 KB
    __shared__ int      lds_idx[4][64];             // 1 KB
    __shared__ float    lds_part[4];
    // total ~34 KB -> 4 blocks/CU (LDS-limited at 139/160 KB)

    const int s    = blockIdx.x & (SS - 1);
    const int n0b  = (blockIdx.x >> 5) * 256;
    const int tid  = threadIdx.x;
    const int wv   = tid >> 6;
    const int lane = tid & 63;
    const int col  = lane & 15;
    const int quad = lane >> 4;

    const float* __restrict__ Ws = W + (size_t)s * KK * DD;
    const int n0w = n0b + wv * 64;

    // ---- A-fragments: (-2*z) split into f16 hi/lo. A[m=col][d=quad*8+j]. ----
    half8 zh[RG], zl[RG];
    #pragma unroll
    for (int rg = 0; rg < RG; ++rg) {
        const float* zp = z + (size_t)(n0w + rg * 16 + col) * (SS * DD) + s * DD + quad * 8;
        const float4 va = ((const float4*)zp)[0];
        const float4 vb = ((const float4*)zp)[1];
        const float src[8] = {va.x, va.y, va.z, va.w, vb.x, vb.y, vb.z, vb.w};
        #pragma unroll
        for (int j = 0; j < 8; ++j) {
            const float v = -2.0f * src[j];
            const _Float16 h = (_Float16)v;
            zh[rg][j] = h;
            zl[rg][j] = (_Float16)(v - (float)h);
        }
    }

    // Staging source: thread covers k-rows (chunk*128 + {0,64} + wv*16 + col), d=quad*8..+7.
    const float* __restrict__ stg = Ws + ((size_t)(wv * 16 + col)) * DD + quad * 8;

    floatx4 best[RG];
    int bi[RG][4];
    #pragma unroll
    for (int rg = 0; rg < RG; ++rg) {
        best[rg] = (floatx4){INFINITY, INFINITY, INFINITY, INFINITY};
        bi[rg][0] = bi[rg][1] = bi[rg][2] = bi[rg][3] = 0;
    }

    // conversion+store of one 8-float group into tile `tile` of buffer `nb`
    auto cvt_store = [&](const float4& va, const float4& vb, int nb, int tile) {
        const float src[8] = {va.x, va.y, va.z, va.w, vb.x, vb.y, vb.z, vb.w};
        half8 h8, l8; float ps = 0.0f;
        #pragma unroll
        for (int j = 0; j < 8; ++j) {
            const float v = src[j];
            ps = fmaf(v, v, ps);
            const _Float16 h = (_Float16)v;
            h8[j] = h;
            l8[j] = (_Float16)(v - (float)h);
        }
        ps += __shfl_xor(ps, 16, 64);
        ps += __shfl_xor(ps, 32, 64);
        *(half8*)&bufH[nb][tile][lane][0] = h8;
        *(half8*)&bufL[nb][tile][lane][0] = l8;
        if (quad == 0) w2b[nb][tile * 16 + col] = ps;
    };

    // ---- prologue: stage chunk 0 (two 64-k halves) ----
    float4 pa = ((const float4*)stg)[0];
    float4 pb = ((const float4*)stg)[1];
    float4 pc = ((const float4*)(stg + 64 * DD))[0];
    float4 pd = ((const float4*)(stg + 64 * DD))[1];
    cvt_store(pa, pb, 0, wv);
    cvt_store(pc, pd, 0, 4 + wv);
    __syncthreads();

    // ---- main K loop, double-buffered, rolling B-fragment preload ----
    for (int c = 0; c < NCHUNK; ++c) {
        const int b = c & 1;
        if (c + 1 < NCHUNK) {   // issue next chunk's global loads early
            const float* nsrc = stg + (size_t)(c + 1) * CHUNK_K * DD;
            pa = ((const float4*)nsrc)[0];
            pb = ((const float4*)nsrc)[1];
            pc = ((const float4*)(nsrc + 64 * DD))[0];
            pd = ((const float4*)(nsrc + 64 * DD))[1];
        }

        // preload tile 0 fragments
        half8 bh0 = *(const half8*)&bufH[b][0][lane][0];
        half8 bl0 = *(const half8*)&bufL[b][0][lane][0];
        float w20 = w2b[b][col];

        #pragma unroll
        for (int tt = 0; tt < CH_TILES; ++tt) {
            half8 nbh, nbl; float nw2 = 0.0f;
            if (tt + 1 < CH_TILES) {   // rolling preload: hide ds_read under MFMAs
                nbh = *(const half8*)&bufH[b][tt + 1][lane][0];
                nbl = *(const half8*)&bufL[b][tt + 1][lane][0];
                nw2 = w2b[b][(tt + 1) * 16 + col];
            }
            const floatx4 c0 = {w20, w20, w20, w20};
            const int tk = c * CH_TILES + tt;

            floatx4 acc[RG];
            __builtin_amdgcn_s_setprio(1);
            #pragma unroll
            for (int rg = 0; rg < RG; ++rg)   // 4 independent MFMAs
                acc[rg] = __builtin_amdgcn_mfma_f32_16x16x32_f16(zh[rg], bh0, c0, 0, 0, 0);
            #pragma unroll
            for (int rg = 0; rg < RG; ++rg)
                acc[rg] = __builtin_amdgcn_mfma_f32_16x16x32_f16(zl[rg], bh0, acc[rg], 0, 0, 0);
            #pragma unroll
            for (int rg = 0; rg < RG; ++rg)
                acc[rg] = __builtin_amdgcn_mfma_f32_16x16x32_f16(zh[rg], bl0, acc[rg], 0, 0, 0);
            __builtin_amdgcn_s_setprio(0);

            #pragma unroll
            for (int rg = 0; rg < RG; ++rg) {
                #pragma unroll
                for (int i = 0; i < 4; ++i) {
                    if (acc[rg][i] < best[rg][i]) { best[rg][i] = acc[rg][i]; bi[rg][i] = tk; }  // strict <
                }
            }
            bh0 = nbh; bl0 = nbl; w20 = nw2;
        }

        if (c + 1 < NCHUNK) {
            const int nb = (c + 1) & 1;
            cvt_store(pa, pb, nb, wv);
            cvt_store(pc, pd, nb, 4 + wv);
            __syncthreads();
        }
    }

    // ---- cross-lane argmin over the 16 k-columns; lower k wins ties ----
    #pragma unroll
    for (int rg = 0; rg < RG; ++rg) {
        #pragma unroll
        for (int i = 0; i < 4; ++i) {
            float v = best[rg][i];
            int   k = bi[rg][i] * 16 + col;
            #pragma unroll
            for (int m = 1; m < 16; m <<= 1) {
                const float vo = __shfl_xor(v, m, 64);
                const int   ko = __shfl_xor(k, m, 64);
                if (vo < v || (vo == v && ko < k)) { v = vo; k = ko; }
            }
            if (col == 0) lds_idx[wv][rg * 16 + quad * 4 + i] = k;  // row-in-wave
        }
    }
    __syncthreads();

    // ---- epilogue: 1 lane per n-row (32 floats); zq = fp32 W[s,k*] ----
    const int krow = lds_idx[wv][lane];
    const float* wsrc = Ws + (size_t)krow * DD;
    const size_t zoff = (size_t)(n0w + lane) * (SS * DD) + s * DD;
    const float* zsrc = z + zoff;
    float* od = out + zoff;
    float sq = 0.0f;
    #pragma unroll
    for (int cc = 0; cc < 8; ++cc) {
        const float4 wq = ((const float4*)wsrc)[cc];
        const float4 zv = ((const float4*)zsrc)[cc];
        const float d0 = wq.x - zv.x, d1 = wq.y - zv.y;
        const float d2 = wq.z - zv.z, d3 = wq.w - zv.w;
        sq = fmaf(d0, d0, sq); sq = fmaf(d1, d1, sq);
        sq = fmaf(d2, d2, sq); sq = fmaf(d3, d3, sq);
        ((float4*)od)[cc] = wq;
    }
    #pragma unroll
    for (int off = 32; off > 0; off >>= 1) sq += __shfl_down(sq, off, 64);

    // per-block partial -> distinct address; NO same-address atomics
    if (lane == 0) lds_part[wv] = sq;
    __syncthreads();
    if (tid == 0)
        part[blockIdx.x] = lds_part[0] + lds_part[1] + lds_part[2] + lds_part[3];
}

// Tiny final reduce: 1 block sums the 1024 per-block partials.
__global__ __launch_bounds__(256) void vq_loss(const float* __restrict__ part,
                                               float* __restrict__ out) {
    __shared__ float l[4];
    const int tid = threadIdx.x;
    float sum = 0.0f;
    #pragma unroll
    for (int i = 0; i < NBLOCKS / 256; ++i) sum += part[tid + i * 256];
    #pragma unroll
    for (int off = 32; off > 0; off >>= 1) sum += __shfl_down(sum, off, 64);
    if ((tid & 63) == 0) l[tid >> 6] = sum;
    __syncthreads();
    if (tid == 0) out[OUT_ELEMS] = (l[0] + l[1] + l[2] + l[3]) * LOSS_SCALE;
}

extern "C" void kernel_launch(void* const* d_in, const int* in_sizes, int n_in,
                              void* d_out, int out_size, void* d_ws, size_t ws_size,
                              hipStream_t stream) {
    const float* z = (const float*)d_in[0];   // (8192, 1024) fp32
    const float* W = (const float*)d_in[1];   // (32, 1024, 32) fp32
    float* out  = (float*)d_out;              // 8388608 zq_st + 1 loss
    float* part = (float*)d_ws;               // NBLOCKS per-block partials (4 KB)

    // 1024 blocks: blockIdx&31 = s, blockIdx>>5 = 256-row n-tile.
    // Every block writes part[blockIdx] unconditionally -> no memset needed.
    vq_fused<<<dim3(NBLOCKS), dim3(256), 0, stream>>>(z, W, out, part);
    vq_loss<<<dim3(1), dim3(256), 0, stream>>>(part, out);
}

// Round 2
// 149.591 us; speedup vs baseline: 2.7463x; 2.7463x over previous
//
#include <hip/hip_runtime.h>
#include <math.h>

// Problem constants (fixed by reference setup_inputs)
#define NN 8192
#define SS 32
#define DD 32
#define KK 1024
#define OUT_ELEMS ((size_t)NN * SS * DD)   // 8388608; loss scalar at out[OUT_ELEMS]

// loss = S * (1 + BETA) * sum_sq / (N*S*D)
#define LOSS_SCALE (32.0f * 1.001f / 8388608.0f)

typedef _Float16 half8 __attribute__((ext_vector_type(8)));
typedef float   floatx4 __attribute__((ext_vector_type(4)));

#define CH_TILES 8                    // k-tiles of 16 per chunk
#define CHUNK_K  (CH_TILES * 16)      // 128 codewords per chunk
#define NCHUNK   (KK / CHUNK_K)       // 8 chunks -> 8 barriers
#define RG 2                          // 16-row groups per wave -> 32 rows/wave
#define WAVES 8                       // 512-thread blocks
#define BLK_ROWS (WAVES * RG * 16)    // 256 rows per block
#define NBLOCKS ((NN / BLK_ROWS) * SS) // 1024 main blocks

// SESSION NOTE (R8): R7 regressed 85->347us from register SPILL (WRITE_SIZE
// 33->925MB = scratch traffic; VGPR capped at 64). Reverted to RG=2 and
// removed register pressure instead of adding it: W's f16 hi/lo split + |w|^2
// are PRECOMPUTED once (w_pre kernel) in MFMA-fragment order, so main-loop
// staging is 2-3 global_load_lds instrs/wave/chunk (zero VALU, zero staging
// regs, no ds_write). 512-thr blocks, 34KB LDS -> 3 blocks/CU, 8 barriers.
// Theory: R6's 85us @ MfmaUtil 26% vs 24.8us MFMA floor = pipe starved by
// barrier convoys + redundant per-chunk W conversion; this removes both.

// ---- workspace layout (d_ws): needs ~4.14 MB ----
#define W2P_OFF  4096                          // part[NBLOCKS] lives at 0
#define WHP_OFF  (W2P_OFF + SS * KK * 4)       // w2P: 128 KB
#define WLP_OFF  (WHP_OFF + SS * KK * DD * 2)  // WhP: 2 MB, WlP: 2 MB

typedef const __attribute__((address_space(1))) void* gas_p;
typedef __attribute__((address_space(3))) void* las_p;

__device__ __forceinline__ void gll16(const void* g, void* l) {
    __builtin_amdgcn_global_load_lds((gas_p)g, (las_p)l, 16, 0, 0);
}
__device__ __forceinline__ void gll4(const void* g, void* l) {
    __builtin_amdgcn_global_load_lds((gas_p)g, (las_p)l, 4, 0, 0);
}

// ---- one-time W preprocossing: f16 hi/lo split + row norms, fragment order ----
// Output WhP/WlP layout: [s][tile g=0..63][lane l=0..63][8 halves], where the
// 16B group at (s,g,l) holds codeword k = g*16 + (l&15), dims d = (l>>4)*8..+7
// == exactly the bytes one wave's global_load_lds(16) needs for one B-tile.
__global__ __launch_bounds__(256) void w_pre(const float* __restrict__ W,
                                             _Float16* __restrict__ WhP,
                                             _Float16* __restrict__ WlP,
                                             float* __restrict__ w2P) {
    const int u    = blockIdx.x * 256 + threadIdx.x;   // 0..131071
    const int s    = u >> 12;
    const int g    = (u >> 6) & 63;
    const int l    = u & 63;
    const int col  = l & 15;
    const int quad = l >> 4;
    const int k    = g * 16 + col;
    const float* src = W + ((size_t)s * KK + k) * DD + quad * 8;
    const float4 va = ((const float4*)src)[0];
    const float4 vb = ((const float4*)src)[1];
    const float v[8] = {va.x, va.y, va.z, va.w, vb.x, vb.y, vb.z, vb.w};
    half8 h8, l8; float ps = 0.0f;
    #pragma unroll
    for (int j = 0; j < 8; ++j) {
        const float x = v[j];
        ps = fmaf(x, x, ps);
        const _Float16 h = (_Float16)x;
        h8[j] = h;
        l8[j] = (_Float16)(x - (float)h);
    }
    ps += __shfl_xor(ps, 16, 64);
    ps += __shfl_xor(ps, 32, 64);
    *(half8*)(WhP + (size_t)u * 8) = h8;
    *(half8*)(WlP + (size_t)u * 8) = l8;
    if (quad == 0) w2P[s * KK + k] = ps;   // w2P[s][k] linear
}

__global__ __launch_bounds__(512, 4) void vq_fused(const float* __restrict__ z,
                                                   const float* __restrict__ W,
                                                   const _Float16* __restrict__ WhP,
                                                   const _Float16* __restrict__ WlP,
                                                   const float* __restrict__ w2P,
                                                   float* __restrict__ out,
                                                   float* __restrict__ part) {
    __shared__ _Float16 bufH[2][CH_TILES][64][8];   // 16 KB
    __shared__ _Float16 bufL[2][CH_TILES][64][8];   // 16 KB
    __shared__ float    w2b[2][CHUNK_K];            // 1 KB
    __shared__ int      lds_idx[WAVES][32];         // 1 KB
    __shared__ float    lds_part[WAVES];
    // ~34.3 KB -> 3 blocks/CU (LDS), 24 waves/CU

    const int s    = blockIdx.x & (SS - 1);
    const int n0b  = (blockIdx.x >> 5) * BLK_ROWS;
    const int tid  = threadIdx.x;
    const int wv   = tid >> 6;
    const int lane = tid & 63;
    const int col  = lane & 15;
    const int quad = lane >> 4;

    const float* __restrict__ Ws = W + (size_t)s * KK * DD;
    const int n0w = n0b + wv * (RG * 16);

    // ---- A-fragments: (-2*z) split into f16 hi/lo. A[m=col][d=quad*8+j]. ----
    half8 zh[RG], zl[RG];
    #pragma unroll
    for (int rg = 0; rg < RG; ++rg) {
        const float* zp = z + (size_t)(n0w + rg * 16 + col) * (SS * DD) + s * DD + quad * 8;
        const float4 va = ((const float4*)zp)[0];
        const float4 vb = ((const float4*)zp)[1];
        const float src[8] = {va.x, va.y, va.z, va.w, vb.x, vb.y, vb.z, vb.w};
        #pragma unroll
        for (int j = 0; j < 8; ++j) {
            const float v = -2.0f * src[j];
            const _Float16 h = (_Float16)v;
            zh[rg][j] = h;
            zl[rg][j] = (_Float16)(v - (float)h);
        }
    }

    floatx4 best[RG];
    int bi[RG][4];
    #pragma unroll
    for (int rg = 0; rg < RG; ++rg) {
        best[rg] = (floatx4){INFINITY, INFINITY, INFINITY, INFINITY};
        bi[rg][0] = bi[rg][1] = bi[rg][2] = bi[rg][3] = 0;
    }

    // per-lane staging sources (pre-converted, fragment-ordered)
    const _Float16* whs = WhP + (size_t)s * 64 * 512 + (size_t)lane * 8;
    const _Float16* wls = WlP + (size_t)s * 64 * 512 + (size_t)lane * 8;
    const float*    w2s = w2P + (size_t)s * KK + lane;

    // stage chunk c into buffer nb: each wave 1 tile (H+L), waves 0-1 do w2.
    // LDS dests are linear lane*width from a wave-uniform base (m104 rule).
    auto stage = [&](int c, int nb) {
        const size_t t = (size_t)c * CH_TILES + wv;     // global tile index
        gll16(whs + t * 512, &bufH[nb][wv][0][0]);
        gll16(wls + t * 512, &bufL[nb][wv][0][0]);
        if (wv < 2) gll4(w2s + c * CHUNK_K + wv * 64, &w2b[nb][wv * 64]);
    };

    // ---- prologue: stage chunk 0 (barrier drains vmcnt -> data visible) ----
    stage(0, 0);
    __syncthreads();

    // ---- main K loop, double-buffered ----
    for (int c = 0; c < NCHUNK; ++c) {
        const int b = c & 1;
        if (c + 1 < NCHUNK) stage(c + 1, b ^ 1);   // issue early; lands under compute

        // rolling one-tile fragment preload (hides ds_read latency)
        half8 bh = *(const half8*)&bufH[b][0][lane][0];
        half8 bl = *(const half8*)&bufL[b][0][lane][0];
        float w2v = w2b[b][col];
        #pragma unroll
        for (int tt = 0; tt < CH_TILES; ++tt) {
            half8 nbh = bh, nbl = bl; float nw2 = w2v;
            if (tt + 1 < CH_TILES) {
                nbh = *(const half8*)&bufH[b][tt + 1][lane][0];
                nbl = *(const half8*)&bufL[b][tt + 1][lane][0];
                nw2 = w2b[b][(tt + 1) * 16 + col];
            }
            const floatx4 c0 = {w2v, w2v, w2v, w2v};
            const int tk = c * CH_TILES + tt;
            __builtin_amdgcn_s_setprio(1);
            floatx4 a0 = __builtin_amdgcn_mfma_f32_16x16x32_f16(zh[0], bh, c0, 0, 0, 0);
            floatx4 a1 = __builtin_amdgcn_mfma_f32_16x16x32_f16(zh[1], bh, c0, 0, 0, 0);
            a0 = __builtin_amdgcn_mfma_f32_16x16x32_f16(zl[0], bh, a0, 0, 0, 0);
            a1 = __builtin_amdgcn_mfma_f32_16x16x32_f16(zl[1], bh, a1, 0, 0, 0);
            a0 = __builtin_amdgcn_mfma_f32_16x16x32_f16(zh[0], bl, a0, 0, 0, 0);
            a1 = __builtin_amdgcn_mfma_f32_16x16x32_f16(zh[1], bl, a1, 0, 0, 0);
            __builtin_amdgcn_s_setprio(0);
            #pragma unroll
            for (int i = 0; i < 4; ++i) {   // strict <, lowest tile wins ties
                if (a0[i] < best[0][i]) { best[0][i] = a0[i]; bi[0][i] = tk; }
                if (a1[i] < best[1][i]) { best[1][i] = a1[i]; bi[1][i] = tk; }
            }
            bh = nbh; bl = nbl; w2v = nw2;
        }
        if (c + 1 < NCHUNK) __syncthreads();
    }

    // ---- cross-lane argmin over the 16 k-columns; lower k wins ties ----
    #pragma unroll
    for (int rg = 0; rg < RG; ++rg) {
        #pragma unroll
        for (int i = 0; i < 4; ++i) {
            float v = best[rg][i];
            int   k = bi[rg][i] * 16 + col;
            #pragma unroll
            for (int m = 1; m < 16; m <<= 1) {
                const float vo = __shfl_xor(v, m, 64);
                const int   ko = __shfl_xor(k, m, 64);
                if (vo < v || (vo == v && ko < k)) { v = vo; k = ko; }
            }
            if (col == 0) lds_idx[wv][rg * 16 + quad * 4 + i] = k;  // row-in-wave
        }
    }
    __syncthreads();

    // ---- epilogue: 2 lanes per n-row (16 floats each); zq = fp32 W[s,k*] ----
    const int r  = lane & 31;
    const int dh = (lane >> 5) * 16;
    const int krow = lds_idx[wv][r];
    const float* wsrc = Ws + (size_t)krow * DD + dh;
    const size_t zoff = (size_t)(n0w + r) * (SS * DD) + s * DD + dh;
    const float* zsrc = z + zoff;
    float* od = out + zoff;
    float sq = 0.0f;
    #pragma unroll
    for (int cc = 0; cc < 4; ++cc) {
        const float4 wq = ((const float4*)wsrc)[cc];
        const float4 zv = ((const float4*)zsrc)[cc];
        const float d0 = wq.x - zv.x, d1 = wq.y - zv.y;
        const float d2 = wq.z - zv.z, d3 = wq.w - zv.w;
        sq = fmaf(d0, d0, sq); sq = fmaf(d1, d1, sq);
        sq = fmaf(d2, d2, sq); sq = fmaf(d3, d3, sq);
        ((float4*)od)[cc] = wq;
    }
    #pragma unroll
    for (int off = 32; off > 0; off >>= 1) sq += __shfl_down(sq, off, 64);

    // per-block partial -> distinct address; NO same-address atomics
    if (lane == 0) lds_part[wv] = sq;
    __syncthreads();
    if (tid == 0) {
        float t = 0.0f;
        #pragma unroll
        for (int w = 0; w < WAVES; ++w) t += lds_part[w];
        part[blockIdx.x] = t;
    }
}

// Tiny final reduce: 1 block sums the per-block partials.
__global__ __launch_bounds__(256) void vq_loss(const float* __restrict__ part,
                                               float* __restrict__ out) {
    __shared__ float l[4];
    const int tid = threadIdx.x;
    float sum = 0.0f;
    #pragma unroll
    for (int i = 0; i < NBLOCKS / 256; ++i) sum += part[tid + i * 256];
    #pragma unroll
    for (int off = 32; off > 0; off >>= 1) sum += __shfl_down(sum, off, 64);
    if ((tid & 63) == 0) l[tid >> 6] = sum;
    __syncthreads();
    if (tid == 0) out[OUT_ELEMS] = (l[0] + l[1] + l[2] + l[3]) * LOSS_SCALE;
}

extern "C" void kernel_launch(void* const* d_in, const int* in_sizes, int n_in,
                              void* d_out, int out_size, void* d_ws, size_t ws_size,
                              hipStream_t stream) {
    const float* z = (const float*)d_in[0];   // (8192, 1024) fp32
    const float* W = (const float*)d_in[1];   // (32, 1024, 32) fp32
    float* out  = (float*)d_out;              // 8388608 zq_st + 1 loss

    char* ws = (char*)d_ws;                   // needs ~4.14 MB
    float*    part = (float*)ws;              // [0, 4KB)
    float*    w2P  = (float*)(ws + W2P_OFF);  // 128 KB
    _Float16* WhP  = (_Float16*)(ws + WHP_OFF); // 2 MB
    _Float16* WlP  = (_Float16*)(ws + WLP_OFF); // 2 MB

    // one-time W split (4 MB read): 131072 threads
    w_pre<<<dim3(512), dim3(256), 0, stream>>>(W, WhP, WlP, w2P);
    // 1024 blocks: blockIdx&31 = s, blockIdx>>5 = 256-row n-tile.
    vq_fused<<<dim3(NBLOCKS), dim3(512), 0, stream>>>(z, W, WhP, WlP, w2P, out, part);
    vq_loss<<<dim3(1), dim3(256), 0, stream>>>(part, out);
}